// Round 23
// baseline (327.887 us; speedup 1.0000x reference)
//
#include <hip/hip_runtime.h>
#include <hip/hip_bf16.h>
#include <stdint.h>

#define TOKENS 8192
#define NOUT   4096
#define KIN    4096

#define BM 256
#define BN 256
#define BK 64
#define NT (KIN / BK)   // 64 K-tiles

typedef __attribute__((ext_vector_type(8))) short bf16x8;
typedef __attribute__((ext_vector_type(4))) float f32x4;

__device__ __forceinline__ uint32_t rotl32(uint32_t x, int r) {
  return (x << r) | (x >> (32 - r));
}

__device__ __forceinline__ uint16_t f2bf_rne(float f) {
  uint32_t u = __float_as_uint(f);
  u += 0x7FFFu + ((u >> 16) & 1u);
  return (uint16_t)(u >> 16);
}

// Threefry-2x32, 20 rounds — JAX PRNG core.
__device__ __forceinline__ void threefry2x32(uint32_t k0, uint32_t k1,
                                             uint32_t c0, uint32_t c1,
                                             uint32_t& o0, uint32_t& o1) {
  uint32_t ks2 = 0x1BD11BDAu ^ k0 ^ k1;
  uint32_t x0 = c0 + k0;
  uint32_t x1 = c1 + k1;
#define TFR(r) { x0 += x1; x1 = rotl32(x1, (r)); x1 ^= x0; }
  TFR(13) TFR(15) TFR(26) TFR(6)
  x0 += k1;  x1 += ks2 + 1u;
  TFR(17) TFR(29) TFR(16) TFR(24)
  x0 += ks2; x1 += k0 + 2u;
  TFR(13) TFR(15) TFR(26) TFR(6)
  x0 += k0;  x1 += k1 + 3u;
  TFR(17) TFR(29) TFR(16) TFR(24)
  x0 += k1;  x1 += ks2 + 4u;
  TFR(13) TFR(15) TFR(26) TFR(6)
  x0 += ks2; x1 += k0 + 5u;
#undef TFR
  o0 = x0; o1 = x1;
}

// Prep: unchanged from r22 (verified): hydrate 8 elems/thread + NT x loads.
__global__ void prep_kernel(const float* __restrict__ x,
                            uint16_t* __restrict__ xb,
                            uint16_t* __restrict__ W,
                            const int* __restrict__ seed_ptr) {
  uint32_t b = blockIdx.x;
  uint32_t g = b / 3u, r = b % 3u;
  if (r == 0u) {
    uint32_t k1 = (uint32_t)(*seed_ptr);                  // key = (0, seed)
    uint32_t j0 = (g * 256u + threadIdx.x) * 8u;          // 0 .. 2^24-8
    const float scale = 0.03125f;
    const float mn    = -0.015625f;
    union { uint16_t u[8]; bf16x8 v; } rr;
#pragma unroll
    for (int e = 0; e < 8; ++e) {
      uint32_t o0, o1;
      threefry2x32(0u, k1, 0u, j0 + (uint32_t)e, o0, o1);
      uint32_t bits = o0 ^ o1;
      float f = __uint_as_float((bits >> 9) | 0x3F800000u) - 1.0f;
      float v = fmaxf(mn, f * scale + mn);
      rr.u[e] = f2bf_rne(v);
    }
    *(bf16x8*)(W + j0) = rr.v;
  } else {
    uint32_t cg = g * 2u + (r - 1u);
    uint32_t base = (cg * 256u + threadIdx.x) * 8u;
    f32x4 a = __builtin_nontemporal_load((const f32x4*)(x + base));
    f32x4 c = __builtin_nontemporal_load((const f32x4*)(x + base + 4));
    union { uint16_t u[8]; bf16x8 v; } rr;
    rr.u[0] = f2bf_rne(a[0]); rr.u[1] = f2bf_rne(a[1]);
    rr.u[2] = f2bf_rne(a[2]); rr.u[3] = f2bf_rne(a[3]);
    rr.u[4] = f2bf_rne(c[0]); rr.u[5] = f2bf_rne(c[1]);
    rr.u[6] = f2bf_rne(c[2]); rr.u[7] = f2bf_rne(c[3]);
    *(bf16x8*)(xb + base) = rr.v;
  }
}

// ---------------------------------------------------------------------------
// ROUND 23: FAT-WAVE GEMM. 256x256 tile, 4 waves (256 thr, 1 wave/SIMD via
// __launch_bounds__(256,1) -> ~512-reg budget/wave), per-wave output
// 128x128: acc 256 AGPR + ~110 VGPR (beats the r9/r15 2-wave/SIMD spill
// wall). Read amplification drops 3x -> 2x: 128 ds_read_b128 issues/tile
// (was 192) -> port floor 2048 cyc < MFMA floor 2484 -> MFMA-bound.
//
// Per K-tile (buf = kt&1), quadrants (s0,colL),(s0,colH),(s1,colL),(s1,colH):
//   P1: read A(s0) 8 + B_L(s0) 4 | barrier | stage A(kt+1)+B_L(kt+1)->buf^1
//       (12, post-barrier) | LKW(0) | 32 MFMA (s0,L)
//   P2: read B_H(s0) 4 | barrier | stage B_H(kt+1)->buf^1 (4) | LKW(0) |
//       32 MFMA (s0,H)
//   P3: read A(s1) 8 (overwrite) + B_L(s1) 4 | barrier | LKW(0) | 32 MFMA
//   P4: read B_H(s1) 4 | VMW(0) | barrier | LKW(0) | 32 MFMA
// WAR (stages post-barrier): arrival at barrier_1(kt) implies every wave
// completed MFMA_4(kt-1) hence its LKW(0)_4 — so ALL reads of buf^1 from
// tile kt-1 (A,B_L last issued P3; B_H at P4) are complete before any
// stage write can land; B_H stage at P2 is covered a fortiori.
// RAW: VMW(0)@P4 drains this tile's 16 stage-loads; barrier_4 publishes
// cross-wave before tile kt+1's P1 reads. Prologue: stage kt0 (16), VMW(0),
// barrier (r16 lesson). Tail: tile 63 stages nothing (drained @62's P4).
// LDS swizzle identical to r5-r22: linear gload_lds dest + inverse-
// swizzled source (lsw), reads XOR ((row&7)<<4); s1 base = s0 ^ 64 (exact).
// ---------------------------------------------------------------------------
__global__ __launch_bounds__(256, 1)
void gemm_bias_kernel(const uint16_t* __restrict__ A,   // x  bf16 [TOKENS][KIN]
                      const uint16_t* __restrict__ B,   // W  bf16 [NOUT][KIN]
                      const float* __restrict__ bias,
                      float* __restrict__ C) {
  __shared__ uint16_t smem[2][2][16384];   // [buf][A=0/B=1][32KB] = 128 KiB

  const int nwgn = NOUT / BN;                 // 16
  const int nwg  = (TOKENS / BM) * nwgn;      // 512 (divisible by 8)
  int bid = blockIdx.x;
  int cpx = nwg >> 3;
  int swzb = (bid & 7) * cpx + (bid >> 3);    // bijective XCD swizzle
  const int tm = (swzb / nwgn) * BM;
  const int tn = (swzb % nwgn) * BN;

  const int t    = threadIdx.x;               // 0..255
  const int lane = t & 63;
  const int wid  = t >> 6;                    // 0..3
  const int wm   = wid >> 1;                  // 0..1 (row half)
  const int wn   = wid & 1;                   // 0..1 (col half)
  const int fr   = lane & 15;
  const int fq   = lane >> 4;

  const int swzRd = (lane & 7) << 4;                    // row&7 == lane&7 here
  const int lsw   = ((t & 7) ^ ((t >> 3) & 7)) << 4;    // stage src pre-swizzle

  // stage source pointers: thread covers row (t>>3) of each 32-row group
  const char* sA = (const char*)(A + (size_t)(tm + (t >> 3)) * KIN) + lsw;
  const char* sB = (const char*)(B + (size_t)(tn + (t >> 3)) * KIN) + lsw;

  char* const smemB = (char*)&smem[0][0][0];
  char* const dstT  = smemB + t * 16;

  // ds_read byte-bases (buf0, s0); s1 = ^64; buf1 = +65536
  const int rA0 = (wm * 128 + fr) * 128 + ((fq << 4) ^ swzRd);
  const int rB0 = 32768 + (wn * 128 + fr) * 128 + ((fq << 4) ^ swzRd);

  f32x4 acc[8][8] = {};          // [row-frag][col-frag], 256 AGPR
  bf16x8 af[8], bv[8];

  auto g1 = [&](const char* src, char* dst) {
    __builtin_amdgcn_global_load_lds(
        (const __attribute__((address_space(1))) void*)src,
        (__attribute__((address_space(3))) void*)dst, 16, 0, 0);
  };
  // A half-panel: 8 issues (32 KB); B: issues q0..q1 (cols q*32..)
  auto stA = [&](int buf, int off) {
#pragma unroll
    for (int q = 0; q < 8; ++q)
      g1(sA + (size_t)q * 262144 + off, dstT + buf * 65536 + q * 4096);
  };
  auto stB = [&](int buf, int off, int q0, int q1) {
#pragma unroll
    for (int q = 0; q < 8; ++q)
      if (q >= q0 && q <= q1)
        g1(sB + (size_t)q * 262144 + off, dstT + buf * 65536 + 32768 + q * 4096);
  };

#define VMW(N) asm volatile("s_waitcnt vmcnt(" #N ")" ::: "memory")
#define LKW(N) asm volatile("s_waitcnt lgkmcnt(" #N ")" ::: "memory")
#define SB0    __builtin_amdgcn_sched_barrier(0)

#define RD_A(BASE)                                                             \
    _Pragma("unroll")                                                          \
    for (int i_ = 0; i_ < 8; ++i_)                                             \
      af[i_] = *(const bf16x8*)(smemB + (BASE) + i_ * 2048);

#define RD_B(BASE, C0)                                                         \
    _Pragma("unroll")                                                          \
    for (int c_ = (C0); c_ < (C0) + 4; ++c_)                                   \
      bv[c_] = *(const bf16x8*)(smemB + (BASE) + c_ * 2048);

#define MF32(C0)                                                               \
    _Pragma("unroll")                                                          \
    for (int i_ = 0; i_ < 8; ++i_)                                             \
      _Pragma("unroll")                                                        \
      for (int c_ = (C0); c_ < (C0) + 4; ++c_)                                 \
        acc[i_][c_] = __builtin_amdgcn_mfma_f32_16x16x32_bf16(                 \
            af[i_], bv[c_], acc[i_][c_], 0, 0, 0);

  // OFF = byte k-offset of kt+1 relative to pointers. MODE: 0 steady
  // (stage kt+1, VMW(0)@P4); 1 = last tile (no stages, no VMW).
#define KTILE(BUF, OFF, MODE)                                                  \
  {                                                                            \
    const int aB = rA0 + (BUF) * 65536;                                        \
    const int bB = rB0 + (BUF) * 65536;                                        \
    /* P1: (s0, colL) */                                                       \
    RD_A(aB) RD_B(bB, 0)                                                       \
    __builtin_amdgcn_s_barrier();                                              \
    if ((MODE) == 0) { stA((BUF) ^ 1, OFF); stB((BUF) ^ 1, OFF, 0, 3); }       \
    LKW(0); SB0; MF32(0)                                                       \
    /* P2: (s0, colH) */                                                       \
    RD_B(bB, 4)                                                                \
    __builtin_amdgcn_s_barrier();                                              \
    if ((MODE) == 0) stB((BUF) ^ 1, OFF, 4, 7);                                \
    LKW(0); SB0; MF32(4)                                                       \
    /* P3: (s1, colL) — af/bv_L overwritten */                                 \
    RD_A(aB ^ 64) RD_B(bB ^ 64, 0)                                             \
    __builtin_amdgcn_s_barrier();                                              \
    LKW(0); SB0; MF32(0)                                                       \
    /* P4: (s1, colH) — the ONE vm wait per tile */                            \
    RD_B(bB ^ 64, 4)                                                           \
    if ((MODE) == 0) VMW(0);                                                   \
    __builtin_amdgcn_s_barrier();                                              \
    LKW(0); SB0; MF32(4)                                                       \
  }

  // Prologue: stage kt0 -> buf0 fully; drain; publish (r16 lesson).
  stA(0, 0); stB(0, 0, 0, 7);
  VMW(0);
  __builtin_amdgcn_s_barrier();

  for (int it = 0; it < (NT - 2) / 2; ++it) {   // tiles 0..61
    KTILE(0, 128, 0)
    KTILE(1, 256, 0)
    sA += 256; sB += 256;
  }
  KTILE(0, 128, 0)   // tile 62: stages kt63 -> buf1, drains @P4
  KTILE(1, 0, 1)     // tile 63: no stages

#undef KTILE
#undef MF32
#undef RD_B
#undef RD_A
#undef SB0
#undef LKW
#undef VMW

  // ---- Vectorized epilogue (r20 scheme, fat-wave mapping) ----
  // acc[i][c][rr] = C[tm + wm*128 + i*16 + fq*4 + rr][tn + wn*128 + c*16 + fr]
  // (m89/m91-verified). Per-wave private [32][36]-f32 LDS region; dwordx4
  // NT stores (r22), 8 rows x 128 B per instruction.
  __builtin_amdgcn_s_barrier();
  float bb[8];
#pragma unroll
  for (int c = 0; c < 8; ++c)
    bb[c] = bias[tn + wn * 128 + c * 16 + fr];
  float* const eb = (float*)(smemB + wid * 4608);
  const int erow = lane >> 3;          // 0..7
  const int ecol = (lane & 7) * 4;     // 0,4,...,28
#pragma unroll
  for (int cr = 0; cr < 4; ++cr) {
#pragma unroll
    for (int cc = 0; cc < 4; ++cc) {
#pragma unroll
      for (int i2 = 0; i2 < 2; ++i2)
#pragma unroll
        for (int j = 0; j < 2; ++j)
#pragma unroll
          for (int rr = 0; rr < 4; ++rr)
            eb[(i2 * 16 + fq * 4 + rr) * 36 + j * 16 + fr] =
                acc[cr * 2 + i2][cc * 2 + j][rr] + bb[cc * 2 + j];
      __builtin_amdgcn_s_waitcnt(0);  // LDS writes drain before read-back
      const size_t rbase = (size_t)(tm + wm * 128 + cr * 32 + erow);
      float* cp = C + rbase * NOUT + tn + wn * 128 + cc * 32 + ecol;
#pragma unroll
      for (int rb = 0; rb < 4; ++rb) {
        f32x4 v = *(const f32x4*)(eb + (rb * 8 + erow) * 36 + ecol);
        __builtin_nontemporal_store(v, (f32x4*)(cp + (size_t)rb * 8 * NOUT));
      }
      __builtin_amdgcn_s_waitcnt(0);  // reads retired before next overwrite
    }
  }
}

extern "C" void kernel_launch(void* const* d_in, const int* in_sizes, int n_in,
                              void* d_out, int out_size, void* d_ws, size_t ws_size,
                              hipStream_t stream) {
  const float* x    = (const float*)d_in[0];   // [8192][4096] fp32
  const float* bias = (const float*)d_in[1];   // [4096] fp32
  const int*   seed = (const int*)d_in[2];     // [1] int
  float* y = (float*)d_out;                    // [8192][4096] fp32

  // workspace: W bf16 (32 MB) | x bf16 (64 MB) — 96 MB, proven available
  uint16_t* Wb = (uint16_t*)d_ws;
  uint16_t* Xb = Wb + (size_t)NOUT * KIN;

  prep_kernel<<<24576, 256, 0, stream>>>(x, Xb, Wb, seed);

  const int grid = (TOKENS / BM) * (NOUT / BN);   // 512
  gemm_bias_kernel<<<grid, 256, 0, stream>>>(Xb, Wb, bias, y);
}

// Round 24
// 247.489 us; speedup vs baseline: 1.3249x; 1.3249x over previous
//
#include <hip/hip_runtime.h>
#include <hip/hip_bf16.h>
#include <stdint.h>

#define TOKENS 8192
#define NOUT   4096
#define KIN    4096

#define BM 256
#define BN 256
#define BK 64
#define NT (KIN / BK)   // 64 K-tiles

typedef __attribute__((ext_vector_type(8))) short bf16x8;
typedef __attribute__((ext_vector_type(4))) float f32x4;

__device__ __forceinline__ uint32_t rotl32(uint32_t x, int r) {
  return (x << r) | (x >> (32 - r));
}

__device__ __forceinline__ uint16_t f2bf_rne(float f) {
  uint32_t u = __float_as_uint(f);
  u += 0x7FFFu + ((u >> 16) & 1u);
  return (uint16_t)(u >> 16);
}

// Threefry-2x32, 20 rounds — JAX PRNG core.
__device__ __forceinline__ void threefry2x32(uint32_t k0, uint32_t k1,
                                             uint32_t c0, uint32_t c1,
                                             uint32_t& o0, uint32_t& o1) {
  uint32_t ks2 = 0x1BD11BDAu ^ k0 ^ k1;
  uint32_t x0 = c0 + k0;
  uint32_t x1 = c1 + k1;
#define TFR(r) { x0 += x1; x1 = rotl32(x1, (r)); x1 ^= x0; }
  TFR(13) TFR(15) TFR(26) TFR(6)
  x0 += k1;  x1 += ks2 + 1u;
  TFR(17) TFR(29) TFR(16) TFR(24)
  x0 += ks2; x1 += k0 + 2u;
  TFR(13) TFR(15) TFR(26) TFR(6)
  x0 += k0;  x1 += k1 + 3u;
  TFR(17) TFR(29) TFR(16) TFR(24)
  x0 += k1;  x1 += ks2 + 4u;
  TFR(13) TFR(15) TFR(26) TFR(6)
  x0 += ks2; x1 += k0 + 5u;
#undef TFR
  o0 = x0; o1 = x1;
}

// Prep (r21/r22-verified): hydrate 8 elems/thread (16B stores), interleave
// 1:2 with convert; x loads nontemporal (read-once).
__global__ void prep_kernel(const float* __restrict__ x,
                            uint16_t* __restrict__ xb,
                            uint16_t* __restrict__ W,
                            const int* __restrict__ seed_ptr) {
  uint32_t b = blockIdx.x;
  uint32_t g = b / 3u, r = b % 3u;
  if (r == 0u) {
    uint32_t k1 = (uint32_t)(*seed_ptr);                  // key = (0, seed)
    uint32_t j0 = (g * 256u + threadIdx.x) * 8u;          // 0 .. 2^24-8
    const float scale = 0.03125f;
    const float mn    = -0.015625f;
    union { uint16_t u[8]; bf16x8 v; } rr;
#pragma unroll
    for (int e = 0; e < 8; ++e) {
      uint32_t o0, o1;
      threefry2x32(0u, k1, 0u, j0 + (uint32_t)e, o0, o1);
      uint32_t bits = o0 ^ o1;
      float f = __uint_as_float((bits >> 9) | 0x3F800000u) - 1.0f;
      float v = fmaxf(mn, f * scale + mn);
      rr.u[e] = f2bf_rne(v);
    }
    *(bf16x8*)(W + j0) = rr.v;
  } else {
    uint32_t cg = g * 2u + (r - 1u);
    uint32_t base = (cg * 256u + threadIdx.x) * 8u;
    f32x4 a = __builtin_nontemporal_load((const f32x4*)(x + base));
    f32x4 c = __builtin_nontemporal_load((const f32x4*)(x + base + 4));
    union { uint16_t u[8]; bf16x8 v; } rr;
    rr.u[0] = f2bf_rne(a[0]); rr.u[1] = f2bf_rne(a[1]);
    rr.u[2] = f2bf_rne(a[2]); rr.u[3] = f2bf_rne(a[3]);
    rr.u[4] = f2bf_rne(c[0]); rr.u[5] = f2bf_rne(c[1]);
    rr.u[6] = f2bf_rne(c[2]); rr.u[7] = f2bf_rne(c[3]);
    *(bf16x8*)(xb + base) = rr.v;
  }
}

// ---------------------------------------------------------------------------
// FINAL (r22, session optimum): 256x256 / BK=64 / 8-wave / 16x16x32,
// 4-phase single-barrier schedule + addressing diet + pre-barrier counted
// lgkm + vectorized LDS-transpose epilogue + nontemporal C stores.
// Measured: GEMM 209.9-212 µs (1310 TF, MfmaUtil 61%), 0 bank conflicts,
// WRITE_SIZE = pure output. Proof chain: r13 (schedule), r16/r17 (prologue
// barrier), r18 (lgkm counts), r20 (epilogue), r22 (NT stores).
// ---------------------------------------------------------------------------
__global__ __launch_bounds__(512, 2)
void gemm_bias_kernel(const uint16_t* __restrict__ A,   // x  bf16 [TOKENS][KIN]
                      const uint16_t* __restrict__ B,   // W  bf16 [NOUT][KIN]
                      const float* __restrict__ bias,
                      float* __restrict__ C) {
  __shared__ uint16_t smem[2][2][16384];   // [buf][A=0/B=1][32KB] = 128 KiB

  const int nwgn = NOUT / BN;                 // 16
  const int nwg  = (TOKENS / BM) * nwgn;      // 512 (divisible by 8)
  int bid = blockIdx.x;
  int cpx = nwg >> 3;
  int swzb = (bid & 7) * cpx + (bid >> 3);    // bijective XCD swizzle
  const int tm = (swzb / nwgn) * BM;
  const int tn = (swzb % nwgn) * BN;

  const int t    = threadIdx.x;
  const int lane = t & 63;
  const int wid  = t >> 6;       // 0..7
  const int wm   = wid >> 2;     // 0..1
  const int wn   = wid & 3;      // 0..3
  const int fr   = lane & 15;
  const int fq   = lane >> 4;

  const int swzRd = (lane & 7) << 4;                    // frag-read byte XOR
  const int lsw   = ((lane & 7) ^ (lane >> 3)) << 4;    // stage src byte offset

  // loop-carried stage source pointers (+256 B per 2-tile iteration)
  const char* sA  = (const char*)(A + (size_t)(tm + wid * 16 + (lane >> 3)) * KIN) + lsw;
  const char* sB  = (const char*)(B + (size_t)(tn + wid * 16 + (lane >> 3)) * KIN) + lsw;
  const char* sA1 = sA + (size_t)128 * KIN * 2;   // +128 rows (half 1)
  const char* sB1 = sB + (size_t)128 * KIN * 2;

  char* const smemB = (char*)&smem[0][0][0];
  char* const dstB  = smemB + wid * 2048 + lane * 16;

  // ds_read byte-bases (relative to smemB); s1 = s0 ^ 64 (exact)
  const int rA00 = (wm * 64 + fr) * 128 + ((fq << 4) ^ swzRd);  // A buf0 s0
  const int rA01 = rA00 ^ 64;
  const int rA10 = rA00 + 65536;
  const int rA11 = rA10 ^ 64;
  const int rB00 = 32768 + (wn * 32 + fr) * 128 + ((fq << 4) ^ swzRd);
  const int rB01 = rB00 ^ 64;
  const int rB10 = rB00 + 65536;
  const int rB11 = rB10 ^ 64;

  f32x4 acc[8][4] = {};
  bf16x8 af[2][4], bv0[2][2], bv1[2][2];

  auto stage2 = [&](const char* src, char* dst) {
    __builtin_amdgcn_global_load_lds(
        (const __attribute__((address_space(1))) void*)src,
        (__attribute__((address_space(3))) void*)dst, 16, 0, 0);
    __builtin_amdgcn_global_load_lds(
        (const __attribute__((address_space(1))) void*)(src + (size_t)8 * KIN * 2),
        (__attribute__((address_space(3))) void*)(dst + 1024), 16, 0, 0);
  };

#define VMW(N) asm volatile("s_waitcnt vmcnt(" #N ")" ::: "memory")
#define LKW(N) asm volatile("s_waitcnt lgkmcnt(" #N ")" ::: "memory")
#define SB0    __builtin_amdgcn_sched_barrier(0)
#define PRI(p) __builtin_amdgcn_s_setprio(p)

// 4 ds_read_b128: af[S][0..3] from base BASE (+ i*2048 immediates)
#define RD_A4(BASE, S)                                                         \
    _Pragma("unroll")                                                          \
    for (int i_ = 0; i_ < 4; ++i_)                                             \
      af[S][i_] = *(const bf16x8*)(smemB + (BASE) + i_ * 2048);

// 2 ds_read_b128: BV[S][0..1] from base BASE
#define RD_B2(BASE, BV, S)                                                     \
    _Pragma("unroll")                                                          \
    for (int j_ = 0; j_ < 2; ++j_)                                             \
      BV[S][j_] = *(const bf16x8*)(smemB + (BASE) + j_ * 2048);

// 8 MFMA: k-group S of quadrant (MH,NH)
#define MF8(MH, NH, BV, S)                                                     \
    _Pragma("unroll")                                                          \
    for (int i_ = 0; i_ < 4; ++i_)                                             \
      _Pragma("unroll")                                                        \
      for (int j_ = 0; j_ < 2; ++j_)                                           \
        acc[(MH) * 4 + i_][(NH) * 2 + j_] =                                    \
            __builtin_amdgcn_mfma_f32_16x16x32_bf16(                           \
                af[S][i_], BV[S][j_], acc[(MH) * 4 + i_][(NH) * 2 + j_],       \
                0, 0, 0);

  // OFF1 = byte k-offset of kt+1; OFF2 = kt+2 (relative to pointers).
  // MODE: 0 steady; 1 = kt62 (stage A1(63) only, VMW(0)@P4); 2 = kt63.
#define KTILE(BUF, OFF1, OFF2, MODE)                                           \
  {                                                                            \
    /* P1: reads A0 + B0 (s0 | s1), stage A1(kt+1)->buf^1 */                   \
    RD_A4((BUF) ? rA10 : rA00, 0) RD_B2((BUF) ? rB10 : rB00, bv0, 0)           \
    SB0;                                                                       \
    RD_A4((BUF) ? rA11 : rA01, 1) RD_B2((BUF) ? rB11 : rB01, bv0, 1)           \
    if ((MODE) <= 1) stage2(sA1 + (OFF1),                                      \
                            dstB + ((BUF) ^ 1) * 65536 + 16384);               \
    LKW(8);                                                                    \
    __builtin_amdgcn_s_barrier();                                              \
    LKW(6); SB0; PRI(1); MF8(0, 0, bv0, 0)                                     \
    LKW(0); SB0; MF8(0, 0, bv0, 1) PRI(0);                                     \
    /* P2: reads B1 (s0 | s1) */                                               \
    RD_B2(((BUF) ? rB10 : rB00) + 16384, bv1, 0)                               \
    SB0;                                                                       \
    RD_B2(((BUF) ? rB11 : rB01) + 16384, bv1, 1)                               \
    LKW(2);                                                                    \
    __builtin_amdgcn_s_barrier();                                              \
    LKW(2); SB0; PRI(1); MF8(0, 1, bv1, 0)                                     \
    LKW(0); SB0; MF8(0, 1, bv1, 1) PRI(0);                                     \
    /* P3: reads A1 (s0 | s1, overwrites af), stage A0+B0(kt+2)->buf */        \
    RD_A4(((BUF) ? rA10 : rA00) + 16384, 0)                                    \
    SB0;                                                                       \
    RD_A4(((BUF) ? rA11 : rA01) + 16384, 1)                                    \
    if ((MODE) == 0) { stage2(sA + (OFF2), dstB + (BUF) * 65536);              \
                       stage2(sB + (OFF2), dstB + (BUF) * 65536 + 32768); }    \
    LKW(4);                                                                    \
    __builtin_amdgcn_s_barrier();                                              \
    LKW(4); SB0; PRI(1); MF8(1, 1, bv1, 0)                                     \
    LKW(0); SB0; MF8(1, 1, bv1, 1) PRI(0);                                     \
    /* P4: stage B1(kt+2)->buf | the ONE vm wait | barrier | cached MFMA */    \
    if ((MODE) == 0) stage2(sB1 + (OFF2), dstB + (BUF) * 65536 + 49152);       \
    if ((MODE) == 0) { VMW(6); } else if ((MODE) == 1) { VMW(0); }             \
    __builtin_amdgcn_s_barrier();                                              \
    SB0; PRI(1); MF8(1, 0, bv0, 0) MF8(1, 0, bv0, 1) PRI(0);                   \
  }

  // Prologue: kt0 all 4 halves -> buf0, kt1's A0,B0,B1 -> buf1; VMW(6)
  // (14 outstanding -> the 8 oldest = all of kt0 landed) THEN s_barrier
  // to publish cross-wave BEFORE the first KTILE's P1 reads (r16 fix).
  stage2(sA,        dstB);                    // A0 kt0
  stage2(sB,        dstB + 32768);            // B0 kt0
  stage2(sA1,       dstB + 16384);            // A1 kt0
  stage2(sB1,       dstB + 49152);            // B1 kt0
  stage2(sA  + 128, dstB + 65536);            // A0 kt1
  stage2(sB  + 128, dstB + 65536 + 32768);    // B0 kt1
  stage2(sB1 + 128, dstB + 65536 + 49152);    // B1 kt1
  VMW(6);
  __builtin_amdgcn_s_barrier();

  for (int it = 0; it < (NT - 2) / 2; ++it) {   // tiles 0..61
    KTILE(0, 128, 256, 0)
    KTILE(1, 256, 384, 0)
    sA += 256; sB += 256; sA1 += 256; sB1 += 256;
  }
  KTILE(0, 128, 0, 1)   // kt62: stage A1(63) only, drain
  KTILE(1, 0, 0, 2)     // kt63

#undef KTILE
#undef MF8
#undef RD_B2
#undef RD_A4
#undef PRI
#undef SB0
#undef LKW
#undef VMW

  // ---- Vectorized epilogue (r20) + NT stores (r22) ----
  __builtin_amdgcn_s_barrier();
  float* const eb = (float*)(smemB + wid * 4608);
  const int erow = lane >> 3;          // 0..7
  const int ecol = (lane & 7) * 4;     // 0,4,...,28
#pragma unroll
  for (int mh = 0; mh < 2; ++mh) {
#pragma unroll
    for (int nh = 0; nh < 2; ++nh) {
#pragma unroll
      for (int c = 0; c < 2; ++c) {
#pragma unroll
        for (int i2 = 0; i2 < 2; ++i2)
#pragma unroll
          for (int j = 0; j < 2; ++j)
#pragma unroll
            for (int rr = 0; rr < 4; ++rr)
              eb[(i2 * 16 + fq * 4 + rr) * 36 + j * 16 + fr] =
                  acc[mh * 4 + c * 2 + i2][nh * 2 + j][rr] +
                  bias[tn + wn * 32 + nh * 128 + j * 16 + fr];
        __builtin_amdgcn_s_waitcnt(0);  // lgkm drain: writes before reads
        const size_t rbase = (size_t)(tm + wm * 64 + mh * 128 + c * 32 + erow);
        float* cp = C + rbase * NOUT + tn + wn * 32 + nh * 128 + ecol;
#pragma unroll
        for (int rb = 0; rb < 4; ++rb) {
          f32x4 v = *(const f32x4*)(eb + (rb * 8 + erow) * 36 + ecol);
          __builtin_nontemporal_store(v, (f32x4*)(cp + (size_t)rb * 8 * NOUT));
        }
        __builtin_amdgcn_s_waitcnt(0);  // reads retired before next overwrite
      }
    }
  }
}

extern "C" void kernel_launch(void* const* d_in, const int* in_sizes, int n_in,
                              void* d_out, int out_size, void* d_ws, size_t ws_size,
                              hipStream_t stream) {
  const float* x    = (const float*)d_in[0];   // [8192][4096] fp32
  const float* bias = (const float*)d_in[1];   // [4096] fp32
  const int*   seed = (const int*)d_in[2];     // [1] int
  float* y = (float*)d_out;                    // [8192][4096] fp32

  // workspace: W bf16 (32 MB) | x bf16 (64 MB) — 96 MB, proven available
  uint16_t* Wb = (uint16_t*)d_ws;
  uint16_t* Xb = Wb + (size_t)NOUT * KIN;

  // prep: 8192 hydrate-groups + 16384 convert-groups, interleaved 1:2
  prep_kernel<<<24576, 256, 0, stream>>>(x, Xb, Wb, seed);

  const int grid = (TOKENS / BM) * (NOUT / BN);   // 512
  gemm_bias_kernel<<<grid, 512, 0, stream>>>(Xb, Wb, bias, y);
}